// Round 6
// baseline (135.738 us; speedup 1.0000x reference)
//
#include <hip/hip_runtime.h>
#include <math.h>

#define BB 32
#define HB 16            // batches per half
#define NIN 2048
#define NOUT 64
#define DD 16
#define CH 32            // chunks per batch element
#define RPC 64           // rows per chunk (NIN / CH)
#define TPB 256          // 4 waves; half-grid = HB*CH = 512 blocks

typedef float    f4 __attribute__((ext_vector_type(4)));
typedef float    f8 __attribute__((ext_vector_type(8)));
typedef _Float16 h4 __attribute__((ext_vector_type(4)));
typedef _Float16 h8 __attribute__((ext_vector_type(8)));

__device__ __forceinline__ float dot8(f8 a, f8 b) {
    float s01 = fmaf(a[1], b[1], a[0] * b[0]);
    float s23 = fmaf(a[3], b[3], a[2] * b[2]);
    float s45 = fmaf(a[5], b[5], a[4] * b[4]);
    float s67 = fmaf(a[7], b[7], a[6] * b[6]);
    return (s01 + s23) + (s45 + s67);
}

// ---------------- pass 0: stream f32 x (NT), emit fp16 copy, plain sum ----------------
__global__ __launch_bounds__(TPB, 4) void pass0_kernel(
    const float* __restrict__ x, h4* __restrict__ xh, f4* __restrict__ pout, int b0)
{
    const int blk   = blockIdx.x;
    const int chunk = blk & (CH - 1);
    const int b     = b0 + (blk >> 5);
    const int tid   = threadIdx.x;
    const int lane  = tid & 63, wave = tid >> 6;

    f4 acc[4];
    #pragma unroll
    for (int j = 0; j < 4; ++j) acc[j] = f4{0.f, 0.f, 0.f, 0.f};

    const size_t row0 = (size_t)b * NIN + (size_t)chunk * RPC;

    #pragma unroll 2
    for (int r = wave; r < RPC; r += 4) {
        const f4* rp = (const f4*)x + (row0 + r) * 256;
        h4* hp = xh + (row0 + r) * 256;
        #pragma unroll
        for (int j = 0; j < 4; ++j) {
            f4 xv = __builtin_nontemporal_load(&rp[j * 64 + lane]);  // keep f32 out of caches
            acc[j] += xv;
            hp[j * 64 + lane] = __builtin_convertvector(xv, h4);     // xh should stay L3-hot
        }
    }

    __shared__ f4 red[4][256];
    #pragma unroll
    for (int j = 0; j < 4; ++j) red[wave][j * 64 + lane] = acc[j];
    __syncthreads();
    f4 s = (red[0][tid] + red[1][tid]) + (red[2][tid] + red[3][tid]);
    pout[((size_t)(b * CH + chunk)) * 256 + tid] = s;
}

// In-block reduction of previous pass's partials -> v (squash(sum*scale+bias)), into LDS.
__device__ __forceinline__ void compute_v(
    const f4* __restrict__ pin, const float* __restrict__ bias,
    int b, int tid, float scale, float* vsm, float* vout, int dowrite)
{
    f4 s = pin[((size_t)b * CH) * 256 + tid];
    #pragma unroll
    for (int c = 1; c < CH; ++c) s += pin[((size_t)(b * CH + c)) * 256 + tid];
    const f4 bi = ((const f4*)bias)[tid];
    s = s * scale + bi;
    float n2 = s.x * s.x + s.y * s.y + s.z * s.z + s.w * s.w;
    n2 += __shfl_xor(n2, 1);
    n2 += __shfl_xor(n2, 2);
    const float k = n2 / ((1.0f + n2) * sqrtf(n2 + 1e-7f));
    const f4 v = s * k;
    *(f4*)(vsm + tid * 4) = v;
    if (dowrite) ((f4*)vout)[b * 256 + tid] = v;
    __syncthreads();
}

// ---------------- passes 1/2: fp16 x, softmax-weighted sum ----------------
// Lane layout: idx = j*64+lane (j=0,1); n = idx>>1, d-half = idx&1.
// Lane pair (lane, lane^1) holds the full 16-d row of one n.
// MODE 2 uses dot(x,v0)+dot(x,v1) = dot(x, v0+v1).
template <int MODE>
__global__ __launch_bounds__(TPB, 4) void pass_kernel(
    const h8* __restrict__ xh,
    const f4* __restrict__ pin,
    const float* __restrict__ bias,
    const float* __restrict__ v0g,   // MODE2: v0 from global
    float* __restrict__ v0out,       // MODE1: write v0 (chunk==0 blocks)
    f4* __restrict__ pout, int b0)
{
    const int blk   = blockIdx.x;
    const int chunk = blk & (CH - 1);
    const int b     = b0 + (blk >> 5);
    const int tid   = threadIdx.x;
    const int lane  = tid & 63, wave = tid >> 6;

    __shared__ __align__(32) float vsm[1024];
    __shared__ __align__(32) float wsm[1024];
    __shared__ f4 red[4][256];

    const size_t row0 = (size_t)b * NIN + (size_t)chunk * RPC;

    // prefetch first row across the v-computation
    const h8* hp0 = xh + (row0 + wave) * 128;
    h8 hx0 = hp0[lane];
    h8 hx1 = hp0[64 + lane];

    if (MODE == 1) {
        compute_v(pin, bias, b, tid, 1.0f / 64.0f, vsm, v0out, chunk == 0);
    } else {
        *(f4*)(vsm + tid * 4) = ((const f4*)v0g)[b * 256 + tid];
        compute_v(pin, bias, b, tid, 1.0f, wsm, nullptr, 0);   // ends with __syncthreads
    }

    f8 vaf[2];
    #pragma unroll
    for (int j = 0; j < 2; ++j) {
        const int idx = j * 64 + lane;
        vaf[j] = *(const f8*)(vsm + idx * 8);
        if (MODE == 2) vaf[j] += *(const f8*)(wsm + idx * 8);   // v0 + v1
    }

    f8 acc0 = {0.f, 0.f, 0.f, 0.f, 0.f, 0.f, 0.f, 0.f};
    f8 acc1 = acc0;

    #pragma unroll 2
    for (int r = wave; r < RPC; r += 4) {
        const f8 x0 = __builtin_convertvector(hx0, f8);
        const f8 x1 = __builtin_convertvector(hx1, f8);
        if (r + 4 < RPC) {
            const h8* np = xh + (row0 + r + 4) * 128;
            hx0 = np[lane];
            hx1 = np[64 + lane];
        }

        float d0 = dot8(x0, vaf[0]);
        float d1 = dot8(x1, vaf[1]);
        d0 += __shfl_xor(d0, 1);   // combine the two d-halves of each n
        d1 += __shfl_xor(d1, 1);

        // max-free softmax: |logit| small for this data; e^|l| safe in f32
        const float e0 = __expf(d0), e1 = __expf(d1);
        float p = e0 + e1;
        #pragma unroll
        for (int o = 2; o <= 32; o <<= 1) p += __shfl_xor(p, o);  // each n exactly once
        const float inv = __builtin_amdgcn_rcpf(p);
        const float a0 = e0 * inv, a1 = e1 * inv;
        #pragma unroll
        for (int k = 0; k < 8; ++k) acc0[k] = fmaf(x0[k], a0, acc0[k]);
        #pragma unroll
        for (int k = 0; k < 8; ++k) acc1[k] = fmaf(x1[k], a1, acc1[k]);
    }

    // flat float offset for idx is idx*8+k == n*16+d -> f4 slots 2*idx, 2*idx+1
    *(f8*)(&red[wave][lane * 2])       = acc0;
    *(f8*)(&red[wave][128 + lane * 2]) = acc1;
    __syncthreads();
    f4 s = (red[0][tid] + red[1][tid]) + (red[2][tid] + red[3][tid]);
    pout[((size_t)(b * CH + chunk)) * 256 + tid] = s;
}

// ---------------- final: reduce partials2 -> squash -> out ----------------
__global__ __launch_bounds__(256) void finish_kernel(
    const f4* __restrict__ pin, const float* __restrict__ bias, f4* __restrict__ out)
{
    const int b = blockIdx.x;
    const int tid = threadIdx.x;
    f4 s = pin[((size_t)b * CH) * 256 + tid];
    #pragma unroll
    for (int c = 1; c < CH; ++c) s += pin[((size_t)(b * CH + c)) * 256 + tid];
    s = s + ((const f4*)bias)[tid];
    float n2 = s.x * s.x + s.y * s.y + s.z * s.z + s.w * s.w;
    n2 += __shfl_xor(n2, 1);
    n2 += __shfl_xor(n2, 2);
    const float k = n2 / ((1.0f + n2) * sqrtf(n2 + 1e-7f));
    out[b * 256 + tid] = s * k;
}

extern "C" void kernel_launch(void* const* d_in, const int* in_sizes, int n_in,
                              void* d_out, int out_size, void* d_ws, size_t ws_size,
                              hipStream_t stream) {
    const float* x    = (const float*)d_in[0];
    const float* bias = (const float*)d_in[1];
    float* out        = (float*)d_out;

    const size_t XH_BYTES = (size_t)BB * NIN * 1024 * 2;   // 128 MiB fp16 copy (64 MiB/half live)
    h4*    xh = (h4*)d_ws;
    float* pA = (float*)((char*)d_ws + XH_BYTES);
    float* pB = pA + (size_t)BB * CH * 1024;
    float* pC = pB + (size_t)BB * CH * 1024;
    float* v0buf = pC + (size_t)BB * CH * 1024;

    const int HGRID = HB * CH;   // 512 blocks per half

    // Process by batch halves so each half's 64 MiB fp16 working set stays
    // L3-resident across its pass1/pass2 (64 + 128 MiB < 256 MiB Infinity Cache).
    for (int h = 0; h < 2; ++h) {
        const int b0 = h * HB;
        pass0_kernel<<<HGRID, TPB, 0, stream>>>(x, xh, (f4*)pA, b0);
        pass_kernel<1><<<HGRID, TPB, 0, stream>>>((const h8*)xh, (const f4*)pA, bias,
                                                  nullptr, v0buf, (f4*)pB, b0);
        pass_kernel<2><<<HGRID, TPB, 0, stream>>>((const h8*)xh, (const f4*)pB, bias,
                                                  v0buf, nullptr, (f4*)pC, b0);
    }
    finish_kernel<<<BB, 256, 0, stream>>>((const f4*)pC, bias, (f4*)out);
}